// Round 13
// baseline (294.556 us; speedup 1.0000x reference)
//
#include <hip/hip_runtime.h>

#define B_ 32
#define K_ 1024
#define F_ 128
#define E_ 128
#define OUT2_ 125
#define ALPHA_ 0.2f

typedef __bf16 bf16x8_t __attribute__((ext_vector_type(8)));
typedef float  f32x4_t  __attribute__((ext_vector_type(4)));

// ------- x transpose+cvt + scores + (fused) prep ----------------------------
__global__ __launch_bounds__(256) void k_xts(const float* __restrict__ x,
                                             const float* __restrict__ lin_w,
                                             const float* __restrict__ lin_b,
                                             const float* __restrict__ a,
                                             unsigned short* __restrict__ xt,
                                             float* __restrict__ s1,
                                             float* __restrict__ s2) {
    int kt = blockIdx.x;
    int b  = blockIdx.y;
    int t  = threadIdx.x;
    __shared__ float xs[64 * 132];
    __shared__ float red1[4][64], red2[4][64];
    __shared__ float wsl[260];

    // ws: waves 0-1 -> a1 path (f = t), waves 2-3 -> a2 path
    {
        int f = t & 127, sel = t >> 7;
        const float* av = a + sel * 128;
        float acc = 0.f;
#pragma unroll 8
        for (int e = 0; e < E_; ++e) acc += lin_w[e * F_ + f] * av[e];
        wsl[sel * 128 + f] = acc;
        if (t < 2) {
            const float* aw = a + t * 128;
            float c = 0.f;
#pragma unroll 8
            for (int e = 0; e < E_; ++e) c += lin_b[e] * aw[e];
            wsl[256 + t] = c;
        }
    }
    const float* xb = x + ((size_t)b * K_ + kt * 64) * F_;
#pragma unroll
    for (int q = 0; q < 8; ++q) {
        int flat = q * 256 + t;
        int kk = flat >> 5, f4 = flat & 31;
        float4 v = *(const float4*)(xb + (size_t)kk * F_ + f4 * 4);
        xs[kk * 132 + f4 * 4]     = v.x;
        xs[kk * 132 + f4 * 4 + 1] = v.y;
        xs[kk * 132 + f4 * 4 + 2] = v.z;
        xs[kk * 132 + f4 * 4 + 3] = v.w;
    }
    __syncthreads();
    // transpose-pack (bf16) — native casts
    {
        int f = t >> 1, half = t & 1;
        union { __bf16 h[32]; uint4 v[4]; } pack;
#pragma unroll
        for (int i = 0; i < 32; ++i) pack.h[i] = (__bf16)xs[(half * 32 + i) * 132 + f];
        unsigned short* dst = xt + (((size_t)(b * 16 + kt) * 128 + f) * 64 + half * 32);
        uint4* d4 = (uint4*)dst;
#pragma unroll
        for (int i = 0; i < 4; ++i) d4[i] = pack.v[i];
    }
    // scores: row r = t&63, f-segment p = t>>6 (32 f each), reduce via LDS
    {
        int r = t & 63, p = t >> 6;
        const float4* xr = (const float4*)&xs[r * 132 + p * 32];
        const float4* w1 = (const float4*)&wsl[p * 32];
        const float4* w2 = (const float4*)&wsl[128 + p * 32];
        float a1 = 0.f, a2 = 0.f;
#pragma unroll
        for (int q = 0; q < 8; ++q) {
            float4 xv = xr[q];
            float4 wa = w1[q], wb = w2[q];
            a1 += xv.x * wa.x + xv.y * wa.y + xv.z * wa.z + xv.w * wa.w;
            a2 += xv.x * wb.x + xv.y * wb.y + xv.z * wb.z + xv.w * wb.w;
        }
        red1[p][r] = a1; red2[p][r] = a2;
    }
    __syncthreads();
    if (t < 64) {
        s1[(size_t)b * K_ + kt * 64 + t] =
            red1[0][t] + red1[1][t] + red1[2][t] + red1[3][t] + wsl[256];
    } else if (t < 128) {
        int r = t - 64;
        s2[(size_t)b * K_ + kt * 64 + r] =
            red2[0][r] + red2[1][r] + red2[2][r] + red2[3][r] + wsl[257];
    }
}

// ---------------- softmax: one block per (i,b) row, no max pass --------------
__global__ __launch_bounds__(256) void k_softmax(const float* __restrict__ s1,
                                                 const float* __restrict__ s2,
                                                 const float* __restrict__ bias,
                                                 float* __restrict__ att) {
    int i = blockIdx.x >> 5;
    int b = blockIdx.x & 31;
    int t = threadIdx.x;
    float sv = s1[b * K_ + i];
    float4 s2v = ((const float4*)(s2 + b * K_))[t];
    float4 bv  = ((const float4*)(bias + (size_t)i * K_))[t];
    float e[4];
    {
        float v;
        v = sv + s2v.x; v = v > 0.f ? v : ALPHA_ * v; e[0] = __expf(v + bv.x);
        v = sv + s2v.y; v = v > 0.f ? v : ALPHA_ * v; e[1] = __expf(v + bv.y);
        v = sv + s2v.z; v = v > 0.f ? v : ALPHA_ * v; e[2] = __expf(v + bv.z);
        v = sv + s2v.w; v = v > 0.f ? v : ALPHA_ * v; e[3] = __expf(v + bv.w);
    }
    float sum = e[0] + e[1] + e[2] + e[3];
    for (int m = 32; m; m >>= 1) sum += __shfl_xor(sum, m, 64);
    __shared__ float reds[4];
    int wave = t >> 6, lane = t & 63;
    if (lane == 0) reds[wave] = sum;
    __syncthreads();
    sum = reds[0] + reds[1] + reds[2] + reds[3];
    float r = 1.f / sum;
    float4 o; o.x = e[0] * r; o.y = e[1] * r; o.z = e[2] * r; o.w = e[3] * r;
    ((float4*)(att + ((size_t)b * K_ + i) * K_))[t] = o;
}

// ---------------- att@x via bf16 MFMA: A in LDS dbuf, X direct from L2 -------
// Round-11 proven structure. Round-13: NONTEMPORAL att loads (fixed type:
// __builtin_nontemporal_load needs a native ext-vector ptr, not float4) —
// att is read exactly once; its 128MB stream was flushing each XCD's 4MB L2
// and evicting the 1MB xt slice the XCD's blocks re-read 32x. nt loads
// don't allocate -> xt stays L2-resident.
__global__ __launch_bounds__(256, 8) void k_attx(const float* __restrict__ att,
                                                 const unsigned short* __restrict__ xt,
                                                 const float* __restrict__ x,
                                                 unsigned short* __restrict__ ht) {
    int flatb = blockIdx.y * gridDim.x + blockIdx.x;     // [0,1024)
    int swz   = (flatb & 7) * 128 + (flatb >> 3);        // XCD-chunked, bijective
    int b  = swz >> 5;
    int i0 = (swz & 31) * 32;
    int t  = threadIdx.x;
    int wave = t >> 6, lane = t & 63;
    int quad = lane >> 4, l15 = lane & 15;

    __shared__ unsigned short A_s[2][32 * 64];    // bf16, swizzled, dbuf (8KB)

    // A staging: row = t>>3 (32 rows), granule ag = t&7 (8 bf16 each)
    int ar = t >> 3, ag = t & 7;
    const float* asrc = att + ((size_t)b * K_ + i0 + ar) * K_ + ag * 8;
    const int aofs = ar * 64 + 8 * (ag ^ (ar & 7));      // swizzled LDS offset

    // X direct per-lane base: xt[b][kt][row][kk], row = wave*32 + n*16 + l15
    const unsigned short* xb = xt + (size_t)b * 16 * 128 * 64
                             + ((size_t)(wave * 32 + l15)) * 64 + quad * 8;

    f32x4_t acc[2][2];
#pragma unroll
    for (int m = 0; m < 2; ++m)
#pragma unroll
        for (int n = 0; n < 2; ++n) acc[m][n] = (f32x4_t)(0.f);

    // prologue: stage A0 into buf 0 (nontemporal: att is stream-once)
    {
        f32x4_t a0 = __builtin_nontemporal_load((const f32x4_t*)(asrc));
        f32x4_t a1 = __builtin_nontemporal_load((const f32x4_t*)(asrc + 4));
        union { __bf16 h[8]; uint4 v; } p;
        p.h[0] = (__bf16)a0[0]; p.h[1] = (__bf16)a0[1];
        p.h[2] = (__bf16)a0[2]; p.h[3] = (__bf16)a0[3];
        p.h[4] = (__bf16)a1[0]; p.h[5] = (__bf16)a1[1];
        p.h[6] = (__bf16)a1[2]; p.h[7] = (__bf16)a1[3];
        *(uint4*)&A_s[0][aofs] = p.v;
    }
    __syncthreads();

#pragma unroll 2
    for (int kt = 0; kt < 16; ++kt) {
        int cur = kt & 1;
        const unsigned short* xk = xb + (size_t)kt * 128 * 64;
        // issue next A tile loads (coalesced 256B/row, nontemporal)
        f32x4_t an0, an1;
        if (kt < 15) {
            const float* as2 = asrc + (kt + 1) * 64;
            an0 = __builtin_nontemporal_load((const f32x4_t*)(as2));
            an1 = __builtin_nontemporal_load((const f32x4_t*)(as2 + 4));
        }
        bf16x8_t bff[2][2];
#pragma unroll
        for (int kh = 0; kh < 2; ++kh) {
            bff[kh][0] = *(const bf16x8_t*)(xk + kh * 32);
            bff[kh][1] = *(const bf16x8_t*)(xk + 16 * 64 + kh * 32);
        }
        // MFMAs for tile kt: A from LDS[cur], X from registers
#pragma unroll
        for (int kh = 0; kh < 2; ++kh) {
            int g = (kh << 2) | quad;
            bf16x8_t af[2];
#pragma unroll
            for (int m = 0; m < 2; ++m) {
                int row = m * 16 + l15;
                af[m] = *(const bf16x8_t*)&A_s[cur][row * 64 + 8 * (g ^ (row & 7))];
            }
#pragma unroll
            for (int m = 0; m < 2; ++m)
#pragma unroll
                for (int n = 0; n < 2; ++n)
                    acc[m][n] = __builtin_amdgcn_mfma_f32_16x16x32_bf16(af[m], bff[kh][n], acc[m][n], 0, 0, 0);
        }
        // stage next A into buf[cur^1]
        if (kt < 15) {
            union { __bf16 h[8]; uint4 v; } p;
            p.h[0] = (__bf16)an0[0]; p.h[1] = (__bf16)an0[1];
            p.h[2] = (__bf16)an0[2]; p.h[3] = (__bf16)an0[3];
            p.h[4] = (__bf16)an1[0]; p.h[5] = (__bf16)an1[1];
            p.h[6] = (__bf16)an1[2]; p.h[7] = (__bf16)an1[3];
            *(uint4*)&A_s[cur ^ 1][aofs] = p.v;
        }
        __syncthreads();
    }
    // epilogue: ht[b][f][i] = bf16(acc + x residual), 8B packed along i
#pragma unroll
    for (int m = 0; m < 2; ++m) {
#pragma unroll
        for (int n = 0; n < 2; ++n) {
            int f = wave * 32 + n * 16 + l15;
            int ib = i0 + m * 16 + quad * 4;
            union { __bf16 h[4]; ushort4 v; } p;
#pragma unroll
            for (int r = 0; r < 4; ++r) {
                int i = ib + r;
                p.h[r] = (__bf16)(acc[m][n][r] + x[((size_t)b * K_ + i) * F_ + f]);
            }
            *(ushort4*)&ht[((size_t)b * F_ + f) * K_ + ib] = p.v;
        }
    }
}

// ---------------- out2 single-kernel MFMA: per (f16,b): C[o128][f16], K=1024 -
// Replaces split-K out2m + part buffer + out2e. Grid (F/16, B) = 256 blocks
// = full chip; each block runs the whole K=1024 and fuses bias+relu in the
// epilogue. Wave w owns o-tiles m = {2w, 2w+1}; all waves share the 16-f
// n-tile.
__global__ __launch_bounds__(256) void k_out2(const unsigned short* __restrict__ ht,
                                              const float* __restrict__ w2,
                                              const float* __restrict__ b2,
                                              float* __restrict__ out) {
    int b  = blockIdx.y;
    int f0 = blockIdx.x * 16;
    int t  = threadIdx.x;
    int wave = t >> 6, lane = t & 63;
    int quad = lane >> 4, l15 = lane & 15;

    __shared__ unsigned short W_s[128 * 72];   // 128o x 64k
    __shared__ unsigned short H_s[16 * 72];    // 16f  x 64k

    f32x4_t acc[2];
    acc[0] = (f32x4_t)(0.f);
    acc[1] = (f32x4_t)(0.f);

    int wo = t >> 1, wq = t & 1;               // w2: 128 rows, 2 thr/row
    int hf = t >> 3, hq = t & 7;               // ht: 16 rows, 8 thr/row (t<128)

    for (int kt = 0; kt < 16; ++kt) {
        int k0 = kt * 64;
        __syncthreads();
        // W: 128o x 64k fp32 -> bf16 (guard o>=125 -> 0), native casts
        {
            union { __bf16 h[32]; uint4 v[4]; } p;
            if (wo < OUT2_) {
                const float* src = w2 + (size_t)wo * K_ + k0 + wq * 32;
#pragma unroll
                for (int q = 0; q < 8; ++q) {
                    float4 v = *(const float4*)(src + q * 4);
                    p.h[q * 4]     = (__bf16)v.x;
                    p.h[q * 4 + 1] = (__bf16)v.y;
                    p.h[q * 4 + 2] = (__bf16)v.z;
                    p.h[q * 4 + 3] = (__bf16)v.w;
                }
            } else {
#pragma unroll
                for (int q = 0; q < 4; ++q) p.v[q] = make_uint4(0, 0, 0, 0);
            }
            uint4* d = (uint4*)&W_s[wo * 72 + wq * 32];
#pragma unroll
            for (int q = 0; q < 4; ++q) d[q] = p.v[q];
        }
        // H: 16f x 64k bf16 copy (threads 0-127, 1 uint4 each)
        if (t < 128) {
            *(uint4*)&H_s[hf * 72 + hq * 8] =
                *(const uint4*)(ht + ((size_t)b * F_ + f0 + hf) * K_ + k0 + hq * 8);
        }
        __syncthreads();
#pragma unroll
        for (int kh = 0; kh < 2; ++kh) {
            bf16x8_t bf = *(const bf16x8_t*)&H_s[l15 * 72 + kh * 32 + quad * 8];
#pragma unroll
            for (int j = 0; j < 2; ++j) {
                int m = wave * 2 + j;
                bf16x8_t af = *(const bf16x8_t*)&W_s[(m * 16 + l15) * 72 + kh * 32 + quad * 8];
                acc[j] = __builtin_amdgcn_mfma_f32_16x16x32_bf16(af, bf, acc[j], 0, 0, 0);
            }
        }
    }
    // epilogue: out[b][f][o] = relu(acc + b2[o]); col(l15)=f, row=o
    int f = f0 + l15;
    float* orow = out + ((size_t)b * F_ + f) * OUT2_;
#pragma unroll
    for (int j = 0; j < 2; ++j) {
        int ob = (wave * 2 + j) * 16 + quad * 4;
#pragma unroll
        for (int r = 0; r < 4; ++r) {
            int o = ob + r;
            if (o < OUT2_) {
                float v = acc[j][r] + b2[o];
                orow[o] = v > 0.f ? v : 0.f;
            }
        }
    }
}

extern "C" void kernel_launch(void* const* d_in, const int* in_sizes, int n_in,
                              void* d_out, int out_size, void* d_ws, size_t ws_size,
                              hipStream_t stream) {
    const float* x      = (const float*)d_in[0];
    const float* lin_w  = (const float*)d_in[1];
    const float* lin_b  = (const float*)d_in[2];
    const float* a      = (const float*)d_in[3];
    const float* bias   = (const float*)d_in[4];
    const float* lin2_w = (const float*)d_in[5];
    const float* lin2_b = (const float*)d_in[6];

    float* out = (float*)d_out;
    float* h2  = out;                                  // B*F*OUT2
    float* att = out + (size_t)B_ * F_ * OUT2_;        // B*K*K

    // ws: 512 (unused, layout-preserving) | s1 32K | s2 32K | ht bf16 8MB |
    // xt bf16 8MB. total 17,041,408 B == proven footprint.
    float* ws = (float*)d_ws;
    float* s1 = ws + 512;
    float* s2 = ws + 512 + B_ * K_;
    unsigned short* ht = (unsigned short*)(ws + 512 + 2 * B_ * K_);   // B*F*K bf16
    unsigned short* xt = ht + (size_t)B_ * K_ * F_;                   // B*K*F bf16

    k_xts<<<dim3(16, B_), 256, 0, stream>>>(x, lin_w, lin_b, a, xt, s1, s2);
    k_softmax<<<B_ * K_, 256, 0, stream>>>(s1, s2, bias, att);
    k_attx<<<dim3(K_ / 32, B_), 256, 0, stream>>>(att, xt, x, ht);
    k_out2<<<dim3(F_ / 16, B_), 256, 0, stream>>>(ht, lin2_w, lin2_b, h2);
}

// Round 14
// 268.912 us; speedup vs baseline: 1.0954x; 1.0954x over previous
//
#include <hip/hip_runtime.h>

#define B_ 32
#define K_ 1024
#define F_ 128
#define E_ 128
#define OUT2_ 125
#define ALPHA_ 0.2f

typedef __bf16 bf16x8_t __attribute__((ext_vector_type(8)));
typedef float  f32x4_t  __attribute__((ext_vector_type(4)));

// ------- x transpose+cvt + scores + (fused) prep ----------------------------
__global__ __launch_bounds__(256) void k_xts(const float* __restrict__ x,
                                             const float* __restrict__ lin_w,
                                             const float* __restrict__ lin_b,
                                             const float* __restrict__ a,
                                             unsigned short* __restrict__ xt,
                                             float* __restrict__ s1,
                                             float* __restrict__ s2) {
    int kt = blockIdx.x;
    int b  = blockIdx.y;
    int t  = threadIdx.x;
    __shared__ float xs[64 * 132];
    __shared__ float red1[4][64], red2[4][64];
    __shared__ float wsl[260];

    // ws: waves 0-1 -> a1 path (f = t), waves 2-3 -> a2 path
    {
        int f = t & 127, sel = t >> 7;
        const float* av = a + sel * 128;
        float acc = 0.f;
#pragma unroll 8
        for (int e = 0; e < E_; ++e) acc += lin_w[e * F_ + f] * av[e];
        wsl[sel * 128 + f] = acc;
        if (t < 2) {
            const float* aw = a + t * 128;
            float c = 0.f;
#pragma unroll 8
            for (int e = 0; e < E_; ++e) c += lin_b[e] * aw[e];
            wsl[256 + t] = c;
        }
    }
    const float* xb = x + ((size_t)b * K_ + kt * 64) * F_;
#pragma unroll
    for (int q = 0; q < 8; ++q) {
        int flat = q * 256 + t;
        int kk = flat >> 5, f4 = flat & 31;
        float4 v = *(const float4*)(xb + (size_t)kk * F_ + f4 * 4);
        xs[kk * 132 + f4 * 4]     = v.x;
        xs[kk * 132 + f4 * 4 + 1] = v.y;
        xs[kk * 132 + f4 * 4 + 2] = v.z;
        xs[kk * 132 + f4 * 4 + 3] = v.w;
    }
    __syncthreads();
    // transpose-pack (bf16) — native casts
    {
        int f = t >> 1, half = t & 1;
        union { __bf16 h[32]; uint4 v[4]; } pack;
#pragma unroll
        for (int i = 0; i < 32; ++i) pack.h[i] = (__bf16)xs[(half * 32 + i) * 132 + f];
        unsigned short* dst = xt + (((size_t)(b * 16 + kt) * 128 + f) * 64 + half * 32);
        uint4* d4 = (uint4*)dst;
#pragma unroll
        for (int i = 0; i < 4; ++i) d4[i] = pack.v[i];
    }
    // scores: row r = t&63, f-segment p = t>>6 (32 f each), reduce via LDS
    {
        int r = t & 63, p = t >> 6;
        const float4* xr = (const float4*)&xs[r * 132 + p * 32];
        const float4* w1 = (const float4*)&wsl[p * 32];
        const float4* w2 = (const float4*)&wsl[128 + p * 32];
        float a1 = 0.f, a2 = 0.f;
#pragma unroll
        for (int q = 0; q < 8; ++q) {
            float4 xv = xr[q];
            float4 wa = w1[q], wb = w2[q];
            a1 += xv.x * wa.x + xv.y * wa.y + xv.z * wa.z + xv.w * wa.w;
            a2 += xv.x * wb.x + xv.y * wb.y + xv.z * wb.z + xv.w * wb.w;
        }
        red1[p][r] = a1; red2[p][r] = a2;
    }
    __syncthreads();
    if (t < 64) {
        s1[(size_t)b * K_ + kt * 64 + t] =
            red1[0][t] + red1[1][t] + red1[2][t] + red1[3][t] + wsl[256];
    } else if (t < 128) {
        int r = t - 64;
        s2[(size_t)b * K_ + kt * 64 + r] =
            red2[0][r] + red2[1][r] + red2[2][r] + red2[3][r] + wsl[257];
    }
}

// ---------------- softmax: one block per (i,b) row, no max pass --------------
__global__ __launch_bounds__(256) void k_softmax(const float* __restrict__ s1,
                                                 const float* __restrict__ s2,
                                                 const float* __restrict__ bias,
                                                 float* __restrict__ att) {
    int i = blockIdx.x >> 5;
    int b = blockIdx.x & 31;
    int t = threadIdx.x;
    float sv = s1[b * K_ + i];
    float4 s2v = ((const float4*)(s2 + b * K_))[t];
    float4 bv  = ((const float4*)(bias + (size_t)i * K_))[t];
    float e[4];
    {
        float v;
        v = sv + s2v.x; v = v > 0.f ? v : ALPHA_ * v; e[0] = __expf(v + bv.x);
        v = sv + s2v.y; v = v > 0.f ? v : ALPHA_ * v; e[1] = __expf(v + bv.y);
        v = sv + s2v.z; v = v > 0.f ? v : ALPHA_ * v; e[2] = __expf(v + bv.z);
        v = sv + s2v.w; v = v > 0.f ? v : ALPHA_ * v; e[3] = __expf(v + bv.w);
    }
    float sum = e[0] + e[1] + e[2] + e[3];
    for (int m = 32; m; m >>= 1) sum += __shfl_xor(sum, m, 64);
    __shared__ float reds[4];
    int wave = t >> 6, lane = t & 63;
    if (lane == 0) reds[wave] = sum;
    __syncthreads();
    sum = reds[0] + reds[1] + reds[2] + reds[3];
    float r = 1.f / sum;
    float4 o; o.x = e[0] * r; o.y = e[1] * r; o.z = e[2] * r; o.w = e[3] * r;
    ((float4*)(att + ((size_t)b * K_ + i) * K_))[t] = o;
}

// ---------------- att@x via bf16 MFMA: A in LDS dbuf, X direct from L2 -------
// Round-11 EXACT load path (plain float4 loads — they hit the L3 where att
// is resident from k_softmax; round-13 showed nontemporal loads break that
// and cost +44us). A cooperatively staged 256B/row -> bf16 -> swizzled LDS
// dbuf; X per-lane direct from L2-resident xt; 8KB LDS; launch_bounds(256,8).
__global__ __launch_bounds__(256, 8) void k_attx(const float* __restrict__ att,
                                                 const unsigned short* __restrict__ xt,
                                                 const float* __restrict__ x,
                                                 unsigned short* __restrict__ ht) {
    int flatb = blockIdx.y * gridDim.x + blockIdx.x;     // [0,1024)
    int swz   = (flatb & 7) * 128 + (flatb >> 3);        // XCD-chunked, bijective
    int b  = swz >> 5;
    int i0 = (swz & 31) * 32;
    int t  = threadIdx.x;
    int wave = t >> 6, lane = t & 63;
    int quad = lane >> 4, l15 = lane & 15;

    __shared__ unsigned short A_s[2][32 * 64];    // bf16, swizzled, dbuf (8KB)

    // A staging: row = t>>3 (32 rows), granule ag = t&7 (8 bf16 each)
    int ar = t >> 3, ag = t & 7;
    const float* asrc = att + ((size_t)b * K_ + i0 + ar) * K_ + ag * 8;
    const int aofs = ar * 64 + 8 * (ag ^ (ar & 7));      // swizzled LDS offset

    // X direct per-lane base: xt[b][kt][row][kk], row = wave*32 + n*16 + l15
    const unsigned short* xb = xt + (size_t)b * 16 * 128 * 64
                             + ((size_t)(wave * 32 + l15)) * 64 + quad * 8;

    f32x4_t acc[2][2];
#pragma unroll
    for (int m = 0; m < 2; ++m)
#pragma unroll
        for (int n = 0; n < 2; ++n) acc[m][n] = (f32x4_t)(0.f);

    // prologue: stage A0 into buf 0
    {
        float4 a0 = *(const float4*)(asrc);
        float4 a1 = *(const float4*)(asrc + 4);
        union { __bf16 h[8]; uint4 v; } p;
        p.h[0] = (__bf16)a0.x; p.h[1] = (__bf16)a0.y;
        p.h[2] = (__bf16)a0.z; p.h[3] = (__bf16)a0.w;
        p.h[4] = (__bf16)a1.x; p.h[5] = (__bf16)a1.y;
        p.h[6] = (__bf16)a1.z; p.h[7] = (__bf16)a1.w;
        *(uint4*)&A_s[0][aofs] = p.v;
    }
    __syncthreads();

#pragma unroll 2
    for (int kt = 0; kt < 16; ++kt) {
        int cur = kt & 1;
        const unsigned short* xk = xb + (size_t)kt * 128 * 64;
        // issue next A tile loads (coalesced 256B/row) + this tile's X loads
        float4 an0, an1;
        if (kt < 15) {
            const float* as2 = asrc + (kt + 1) * 64;
            an0 = *(const float4*)(as2);
            an1 = *(const float4*)(as2 + 4);
        }
        bf16x8_t bff[2][2];
#pragma unroll
        for (int kh = 0; kh < 2; ++kh) {
            bff[kh][0] = *(const bf16x8_t*)(xk + kh * 32);
            bff[kh][1] = *(const bf16x8_t*)(xk + 16 * 64 + kh * 32);
        }
        // MFMAs for tile kt: A from LDS[cur], X from registers
#pragma unroll
        for (int kh = 0; kh < 2; ++kh) {
            int g = (kh << 2) | quad;
            bf16x8_t af[2];
#pragma unroll
            for (int m = 0; m < 2; ++m) {
                int row = m * 16 + l15;
                af[m] = *(const bf16x8_t*)&A_s[cur][row * 64 + 8 * (g ^ (row & 7))];
            }
#pragma unroll
            for (int m = 0; m < 2; ++m)
#pragma unroll
                for (int n = 0; n < 2; ++n)
                    acc[m][n] = __builtin_amdgcn_mfma_f32_16x16x32_bf16(af[m], bff[kh][n], acc[m][n], 0, 0, 0);
        }
        // stage next A into buf[cur^1]
        if (kt < 15) {
            union { __bf16 h[8]; uint4 v; } p;
            p.h[0] = (__bf16)an0.x; p.h[1] = (__bf16)an0.y;
            p.h[2] = (__bf16)an0.z; p.h[3] = (__bf16)an0.w;
            p.h[4] = (__bf16)an1.x; p.h[5] = (__bf16)an1.y;
            p.h[6] = (__bf16)an1.z; p.h[7] = (__bf16)an1.w;
            *(uint4*)&A_s[cur ^ 1][aofs] = p.v;
        }
        __syncthreads();
    }
    // epilogue: ht[b][f][i] = bf16(acc + x residual), 8B packed along i
#pragma unroll
    for (int m = 0; m < 2; ++m) {
#pragma unroll
        for (int n = 0; n < 2; ++n) {
            int f = wave * 32 + n * 16 + l15;
            int ib = i0 + m * 16 + quad * 4;
            union { __bf16 h[4]; ushort4 v; } p;
#pragma unroll
            for (int r = 0; r < 4; ++r) {
                int i = ib + r;
                p.h[r] = (__bf16)(acc[m][n][r] + x[((size_t)b * K_ + i) * F_ + f]);
            }
            *(ushort4*)&ht[((size_t)b * F_ + f) * K_ + ib] = p.v;
        }
    }
}

// ---------------- out2 single-kernel MFMA: per (f16,b): C[o128][f16], K=1024 -
// Round-14: tested in ISOLATION (round-13 bundled it with the nt regression).
// Replaces split-K out2m + part buffer + out2e: 256 blocks = full chip,
// whole K per block, bias+relu fused.
__global__ __launch_bounds__(256) void k_out2(const unsigned short* __restrict__ ht,
                                              const float* __restrict__ w2,
                                              const float* __restrict__ b2,
                                              float* __restrict__ out) {
    int b  = blockIdx.y;
    int f0 = blockIdx.x * 16;
    int t  = threadIdx.x;
    int wave = t >> 6, lane = t & 63;
    int quad = lane >> 4, l15 = lane & 15;

    __shared__ unsigned short W_s[128 * 72];   // 128o x 64k
    __shared__ unsigned short H_s[16 * 72];    // 16f  x 64k

    f32x4_t acc[2];
    acc[0] = (f32x4_t)(0.f);
    acc[1] = (f32x4_t)(0.f);

    int wo = t >> 1, wq = t & 1;               // w2: 128 rows, 2 thr/row
    int hf = t >> 3, hq = t & 7;               // ht: 16 rows, 8 thr/row (t<128)

    for (int kt = 0; kt < 16; ++kt) {
        int k0 = kt * 64;
        __syncthreads();
        // W: 128o x 64k fp32 -> bf16 (guard o>=125 -> 0), native casts
        {
            union { __bf16 h[32]; uint4 v[4]; } p;
            if (wo < OUT2_) {
                const float* src = w2 + (size_t)wo * K_ + k0 + wq * 32;
#pragma unroll
                for (int q = 0; q < 8; ++q) {
                    float4 v = *(const float4*)(src + q * 4);
                    p.h[q * 4]     = (__bf16)v.x;
                    p.h[q * 4 + 1] = (__bf16)v.y;
                    p.h[q * 4 + 2] = (__bf16)v.z;
                    p.h[q * 4 + 3] = (__bf16)v.w;
                }
            } else {
#pragma unroll
                for (int q = 0; q < 4; ++q) p.v[q] = make_uint4(0, 0, 0, 0);
            }
            uint4* d = (uint4*)&W_s[wo * 72 + wq * 32];
#pragma unroll
            for (int q = 0; q < 4; ++q) d[q] = p.v[q];
        }
        // H: 16f x 64k bf16 copy (threads 0-127, 1 uint4 each)
        if (t < 128) {
            *(uint4*)&H_s[hf * 72 + hq * 8] =
                *(const uint4*)(ht + ((size_t)b * F_ + f0 + hf) * K_ + k0 + hq * 8);
        }
        __syncthreads();
#pragma unroll
        for (int kh = 0; kh < 2; ++kh) {
            bf16x8_t bf = *(const bf16x8_t*)&H_s[l15 * 72 + kh * 32 + quad * 8];
#pragma unroll
            for (int j = 0; j < 2; ++j) {
                int m = wave * 2 + j;
                bf16x8_t af = *(const bf16x8_t*)&W_s[(m * 16 + l15) * 72 + kh * 32 + quad * 8];
                acc[j] = __builtin_amdgcn_mfma_f32_16x16x32_bf16(af, bf, acc[j], 0, 0, 0);
            }
        }
    }
    // epilogue: out[b][f][o] = relu(acc + b2[o]); col(l15)=f, row=o
    int f = f0 + l15;
    float* orow = out + ((size_t)b * F_ + f) * OUT2_;
#pragma unroll
    for (int j = 0; j < 2; ++j) {
        int ob = (wave * 2 + j) * 16 + quad * 4;
#pragma unroll
        for (int r = 0; r < 4; ++r) {
            int o = ob + r;
            if (o < OUT2_) {
                float v = acc[j][r] + b2[o];
                orow[o] = v > 0.f ? v : 0.f;
            }
        }
    }
}

extern "C" void kernel_launch(void* const* d_in, const int* in_sizes, int n_in,
                              void* d_out, int out_size, void* d_ws, size_t ws_size,
                              hipStream_t stream) {
    const float* x      = (const float*)d_in[0];
    const float* lin_w  = (const float*)d_in[1];
    const float* lin_b  = (const float*)d_in[2];
    const float* a      = (const float*)d_in[3];
    const float* bias   = (const float*)d_in[4];
    const float* lin2_w = (const float*)d_in[5];
    const float* lin2_b = (const float*)d_in[6];

    float* out = (float*)d_out;
    float* h2  = out;                                  // B*F*OUT2
    float* att = out + (size_t)B_ * F_ * OUT2_;        // B*K*K

    // ws: 512 (unused, layout-preserving) | s1 32K | s2 32K | ht bf16 8MB |
    // xt bf16 8MB. total 17,041,408 B == proven footprint.
    float* ws = (float*)d_ws;
    float* s1 = ws + 512;
    float* s2 = ws + 512 + B_ * K_;
    unsigned short* ht = (unsigned short*)(ws + 512 + 2 * B_ * K_);   // B*F*K bf16
    unsigned short* xt = ht + (size_t)B_ * K_ * F_;                   // B*K*F bf16

    k_xts<<<dim3(16, B_), 256, 0, stream>>>(x, lin_w, lin_b, a, xt, s1, s2);
    k_softmax<<<B_ * K_, 256, 0, stream>>>(s1, s2, bias, att);
    k_attx<<<dim3(K_ / 32, B_), 256, 0, stream>>>(att, xt, x, ht);
    k_out2<<<dim3(F_ / 16, B_), 256, 0, stream>>>(ht, lin2_w, lin2_b, h2);
}